// Round 11
// baseline (203.442 us; speedup 1.0000x reference)
//
#include <hip/hip_runtime.h>
#include <hip/hip_bf16.h>
#include <cstdint>
#include <cstddef>

// R18: K-fragments direct from global (L2) — bypass LDS for K entirely.
//  R17 post-mortem: attn 46.5us = LDS-unit wall (~450 cyc/wave-iter: 192
//  frag reads + 100 K-DMA writes + 90 V scatter + 64 conflicts; x224
//  wave-iters/CU ~ 42us). 4-way K-read replication can't be fixed by wider
//  waves (R16: VGPR wall). Instead: swapped-QK's A-frag is 16 CONTIGUOUS
//  global bytes (qkv[key*2304+768+head*64+(kt*2+h)*8]) — load the 8 frags
//  per tile straight from global (panel is L2-resident: 16 qt-blocks/XCD
//  share it). Deletes K-DMA, Ks buffer (LDS 34.8->18.4KB), K LDS reads,
//  and ALL hand-counted vmcnt: issue order (va older than kf) lets the
//  compiler emit progressive counted waits itself. kf issued at iter-top so
//  barrier+V-staging hides ~200cyc L2 latency. VGPR ~105-120 peak -> (256,4)
//  holds, 896 blocks co-resident. Spill tripwire: WRITE_SIZE >> 16MB.
// cvt3 (K-prescale) / gemm_qkv / gemm_out / ln unchanged from R17.

typedef __attribute__((ext_vector_type(8))) short short8;
typedef __attribute__((ext_vector_type(4))) short short4_;
typedef __attribute__((ext_vector_type(4))) float float4_;
typedef __attribute__((ext_vector_type(16))) float floatx16;
typedef __attribute__((ext_vector_type(4))) int int4_;

#if __has_builtin(__builtin_amdgcn_exp2f)
#define EXP2(x) __builtin_amdgcn_exp2f(x)
#else
#define EXP2(x) exp2f(x)
#endif

#define QK_SCALE 0.1803368801111244f   // 0.125 * log2(e)

__device__ __forceinline__ float bf2f(short s) {
    unsigned int u = ((unsigned int)(unsigned short)s) << 16;
    float f;
    __builtin_memcpy(&f, &u, 4);
    return f;
}
__device__ __forceinline__ short f2bf(float f) {
    unsigned int u;
    __builtin_memcpy(&u, &f, 4);
    u += 0x7fffu + ((u >> 16) & 1u);   // round-to-nearest-even
    return (short)(u >> 16);
}
__device__ __forceinline__ short8 f8_to_bf8_s(const float* __restrict__ p, float s) {
    float4_ a = *(const float4_*)(p);
    float4_ b = *(const float4_*)(p + 4);
    short8 r;
    r[0] = f2bf(a[0] * s); r[1] = f2bf(a[1] * s);
    r[2] = f2bf(a[2] * s); r[3] = f2bf(a[3] * s);
    r[4] = f2bf(b[0] * s); r[5] = f2bf(b[1] * s);
    r[6] = f2bf(b[2] * s); r[7] = f2bf(b[3] * s);
    return r;
}
__device__ __forceinline__ void gll16(const short* g, short* l) {
    __builtin_amdgcn_global_load_lds(
        (const __attribute__((address_space(1))) unsigned int*)g,
        (__attribute__((address_space(3))) unsigned int*)l, 16, 0, 0);
}
// pack two f32 -> one u32 of 2 bf16 (lo = first arg)
__device__ __forceinline__ int cvtpk(float lo, float hi) {
    int r;
    asm("v_cvt_pk_bf16_f32 %0, %1, %2" : "=v"(r) : "v"(lo), "v"(hi));
    return r;
}

#define LDT 72

// ---- cvt3: fp32->bf16 for x / w_qkv / w_out; scales K-rows of w_qkv ------
__global__ __launch_bounds__(256) void cvt3(
    const float* __restrict__ a, int na, const float* __restrict__ b, int nb,
    const float* __restrict__ c, int nc,
    short* __restrict__ oa, short* __restrict__ ob, short* __restrict__ oc)
{
    int i = (blockIdx.x * 256 + threadIdx.x) * 8;
    if (i < na) {
        *(short8*)&oa[i] = f8_to_bf8_s(a + i, 1.0f);
    } else if (i < na + nb) {
        int j = i - na;
        // w_qkv rows [768,1536) = K section: fold in the softmax scale
        float s = (j >= 768 * 768 && j < 1536 * 768) ? QK_SCALE : 1.0f;
        *(short8*)&ob[j] = f8_to_bf8_s(b + j, s);
    } else {
        int j = i - na - nb;
        if (j < nc) *(short8*)&oc[j] = f8_to_bf8_s(c + j, 1.0f);
    }
}

// ---- gemm_qkv: dilution-aware QKV projection, 128x64 tiles ----------------
// Covered cells only. 1344 blocks: g0 = 768 (64 my x 12 nx, rows stride 1,
// heads 0-3), g1 = 384 (32 x 12, rows 1+2i), g2 = 192 (16 x 12, rows 2+4i).
// gcol = (nx>>2)*768 + g*256 + (nx&3)*64. K-section bias scaled by QK_SCALE
// (W K-rows already scaled in cvt3).
__global__ __launch_bounds__(256) void gemm_qkv(
    const short* __restrict__ A,     // xb [8192,768]
    const short* __restrict__ B,     // wqkvb [2304,768]
    const float* __restrict__ bias,  // b_qkv [2304]
    short* __restrict__ C)           // qkv [8192,2304]
{
    __shared__ short As[128 * 64];   // chunk-swizzled: slot(r,c)=G(r, c^(r&7))
    __shared__ short Bs[64 * 64];

    const int bx = blockIdx.x;
    const int L  = (bx & 7) * 168 + (bx >> 3);   // 1344 = 8 XCDs * 168
    int g, t, rate, off0;
    if (L < 768)       { g = 0; t = L;        rate = 1; off0 = 0; }
    else if (L < 1152) { g = 1; t = L - 768;  rate = 2; off0 = 1; }
    else               { g = 2; t = L - 1152; rate = 4; off0 = 2; }
    const int nx = t % 12, my = t / 12;         // nx fastest: A-panel shared
    const int ncol0 = (nx >> 2) * 768 + g * 256 + (nx & 3) * 64;
    const int m0 = my * 128;                    // local (gathered) row base
    const float bscale = ((nx >> 2) == 1) ? QK_SCALE : 1.0f;

    const int tid  = threadIdx.x;
    const int wave = tid >> 6, lane = tid & 63;
    const int quad = lane >> 4, l16 = lane & 15;
    const int lrow   = lane >> 3;
    const int lchunk = (lane & 7) ^ lrow;

    const short* Abase = A + (size_t)(off0 + (m0 + wave * 32 + lrow) * rate) * 768
                           + lchunk * 8;
    const short* Bbase = B + (size_t)(ncol0 + wave * 16 + lrow) * 768 + lchunk * 8;
    short* AsW = &As[(wave * 32) * 64];
    short* BsW = &Bs[(wave * 16) * 64];
    const size_t arowstep = (size_t)8 * rate * 768;

    float4_ acc[2][4] = {};

    for (int k0 = 0; k0 < 768; k0 += 64) {
        __syncthreads();
        #pragma unroll
        for (int i = 0; i < 4; i++)
            gll16(Abase + (size_t)i * arowstep + k0, AsW + (i * 8) * 64);
        #pragma unroll
        for (int i = 0; i < 2; i++)
            gll16(Bbase + (size_t)(i * 8) * 768 + k0, BsW + (i * 8) * 64);
        __syncthreads();
        #pragma unroll
        for (int ks = 0; ks < 2; ks++) {
            const int ca = ((ks * 4 + quad) ^ (l16 & 7)) * 8;
            short8 af[2], bf[4];
            #pragma unroll
            for (int mt = 0; mt < 2; mt++)
                af[mt] = *(const short8*)&As[(wave * 32 + mt * 16 + l16) * 64 + ca];
            #pragma unroll
            for (int nt = 0; nt < 4; nt++)
                bf[nt] = *(const short8*)&Bs[(nt * 16 + l16) * 64 + ca];
            #pragma unroll
            for (int mt = 0; mt < 2; mt++)
                #pragma unroll
                for (int nt = 0; nt < 4; nt++)
                    acc[mt][nt] = __builtin_amdgcn_mfma_f32_16x16x32_bf16(
                        af[mt], bf[nt], acc[mt][nt], 0, 0, 0);
        }
    }

    #pragma unroll
    for (int nt = 0; nt < 4; nt++) {
        const int gcol = ncol0 + nt * 16 + l16;
        const float bv = bias[gcol] * bscale;
        #pragma unroll
        for (int mt = 0; mt < 2; mt++) {
            #pragma unroll
            for (int r = 0; r < 4; r++) {
                const int rl = m0 + wave * 32 + mt * 16 + quad * 4 + r;
                const size_t grow = (size_t)off0 + (size_t)rl * rate;
                C[grow * 2304 + gcol] = f2bf(acc[mt][nt][r] + bv);
            }
        }
    }
}

// ---- gemm_out: out-projection, 128x64 tiles, fp32 store -------------------
// out[row, col] = LN(o)[row,:768] @ w_out[col,:]^T + b_out[col].
// 768 blocks = 12 nx x 64 my, XCD swizzle 8x96.
__global__ __launch_bounds__(256) void gemm_out(
    const short* __restrict__ A,     // qkv [8192,2304], q section = LN(o)
    const short* __restrict__ B,     // woutb [768,768]
    const float* __restrict__ bias,  // b_out [768]
    float* __restrict__ C)           // out [8192,768] fp32
{
    __shared__ short As[128 * 64];
    __shared__ short Bs[64 * 64];

    const int bx = blockIdx.x;
    const int L  = (bx & 7) * 96 + (bx >> 3);   // 768 = 8 XCDs * 96
    const int nx = L % 12, my = L / 12;
    const int n0 = nx * 64, m0 = my * 128;

    const int tid  = threadIdx.x;
    const int wave = tid >> 6, lane = tid & 63;
    const int quad = lane >> 4, l16 = lane & 15;
    const int lrow   = lane >> 3;
    const int lchunk = (lane & 7) ^ lrow;

    const short* Abase = A + (size_t)(m0 + wave * 32 + lrow) * 2304 + lchunk * 8;
    const short* Bbase = B + (size_t)(n0 + wave * 16 + lrow) * 768 + lchunk * 8;
    short* AsW = &As[(wave * 32) * 64];
    short* BsW = &Bs[(wave * 16) * 64];

    float4_ acc[2][4] = {};

    for (int k0 = 0; k0 < 768; k0 += 64) {
        __syncthreads();
        #pragma unroll
        for (int i = 0; i < 4; i++)
            gll16(Abase + (size_t)(i * 8) * 2304 + k0, AsW + (i * 8) * 64);
        #pragma unroll
        for (int i = 0; i < 2; i++)
            gll16(Bbase + (size_t)(i * 8) * 768 + k0, BsW + (i * 8) * 64);
        __syncthreads();
        #pragma unroll
        for (int ks = 0; ks < 2; ks++) {
            const int ca = ((ks * 4 + quad) ^ (l16 & 7)) * 8;
            short8 af[2], bf[4];
            #pragma unroll
            for (int mt = 0; mt < 2; mt++)
                af[mt] = *(const short8*)&As[(wave * 32 + mt * 16 + l16) * 64 + ca];
            #pragma unroll
            for (int nt = 0; nt < 4; nt++)
                bf[nt] = *(const short8*)&Bs[(nt * 16 + l16) * 64 + ca];
            #pragma unroll
            for (int mt = 0; mt < 2; mt++)
                #pragma unroll
                for (int nt = 0; nt < 4; nt++)
                    acc[mt][nt] = __builtin_amdgcn_mfma_f32_16x16x32_bf16(
                        af[mt], bf[nt], acc[mt][nt], 0, 0, 0);
        }
    }

    #pragma unroll
    for (int nt = 0; nt < 4; nt++) {
        const int col = n0 + nt * 16 + l16;
        const float bv = bias[col];
        #pragma unroll
        for (int mt = 0; mt < 2; mt++) {
            #pragma unroll
            for (int r = 0; r < 4; r++) {
                const int row = m0 + wave * 32 + mt * 16 + quad * 4 + r;
                C[(size_t)row * 768 + col] = acc[mt][nt][r] + bv;
            }
        }
    }
}

// ---- Split-K in-register-P dilated attention, K-direct-from-global --------
// Grid: 896 = 28 sh * 2 half * 16 qt (XCD-chunk swizzled, qt fastest).
// Block 256 = 4 waves; wave w owns q-rows [w*32, w*32+32). 16 K/V tiles of
// 64 keys. K fragments load straight from global (L2-resident panel) into
// regs — no K LDS buffer. V double-buffered in LDS (transpose scatter).
// All waitcnts compiler-managed: issue order (va older than kf) yields
// progressive counted vmcnt automatically. Raw barriers (no vmcnt drain).
// K pre-scaled by QK_SCALE at projection; Q loaded raw.
__global__ __launch_bounds__(256, 4) void dilated_attn(
    const short* __restrict__ qkv, short* __restrict__ obuf1,
    short* __restrict__ obuf2, float* __restrict__ lbuf)
{
    __shared__ short Vt[2 * 64 * LDT];  // Vt[d][key], key cols XOR-swizzled

    const int bx = blockIdx.x;
    const int L  = (bx & 7) * 112 + (bx >> 3);   // 896 = 8 XCDs * 112
    const int qt   = L & 15;
    const int half = (L >> 4) & 1;
    const int sh   = L >> 5;   // 0..27

    int g, seg, s, rate, off0;
    if (sh < 16)      { g = 0; seg = sh >> 2;        s = 2048; rate = 1; off0 = 0; }
    else if (sh < 24) { g = 1; seg = (sh - 16) >> 2; s = 4096; rate = 2; off0 = 1; }
    else              { g = 2; seg = 0;              s = 8192; rate = 4; off0 = 2; }
    const int head = g * 4 + (sh & 3);

    const int tid  = threadIdx.x;
    const int wave = tid >> 6, lane = tid & 63;
    const int h = lane >> 5, l32 = lane & 31;
    const int srow = tid >> 2, scol = (tid & 3) * 16;   // V-staging map

    // ---- Q frags (B-operand of swapped QK): lane (h,l32) holds
    // Q[q = qt*128+wave*32+l32][kt*16 + h*8 + e], raw (K carries the scale).
    const size_t bpos = (size_t)seg * s + off0
                      + (size_t)(qt * 128 + wave * 32) * rate;
    short8 aq[4];
    {
        const short* qsrc = qkv + (bpos + (size_t)l32 * rate) * 2304
                                + head * 64 + h * 8;
        #pragma unroll
        for (int kt = 0; kt < 4; kt++)
            aq[kt] = *(const short8*)(qsrc + kt * 16);
    }

    // K fragment base: frag(t,kt) = 16B at key row (t*32+l32), d-chunk
    // (kt*2+h)*8 — the exact unswizzled image of the old LDS read.
    const size_t kstep = (size_t)64 * rate * 2304;
    const size_t krow32 = (size_t)32 * rate * 2304;
    const size_t kq0 = (size_t)seg * s + off0 + (size_t)(half * 1024) * rate;
    const short* kb = qkv + (kq0 + (size_t)l32 * rate) * 2304
                          + 768 + head * 64 + h * 8;
    const short* vgp = qkv + (kq0 + (size_t)srow * rate) * 2304
                           + 1536 + head * 64 + scol;
    const int vswz = scol;

    // ---- prologue: V0 regs -> Vt[0]; va := V1 (in flight) -----------------
    short8 va0 = *(const short8*)(vgp);
    short8 va1 = *(const short8*)(vgp + 8);
    vgp += kstep;
    #pragma unroll
    for (int e = 0; e < 8; e++) Vt[(scol + e) * LDT + (srow ^ vswz)] = va0[e];
    #pragma unroll
    for (int e = 0; e < 8; e++) Vt[(scol + 8 + e) * LDT + (srow ^ vswz)] = va1[e];
    va0 = *(const short8*)(vgp);      // V tile 1
    va1 = *(const short8*)(vgp + 8);
    vgp += kstep;

    float lsum = 0.f;
    floatx16 oacc[2] = {};

    auto compute = [&](const short* vb, const short8* kf) {
        // S'^T = K' Q^T : sacc[t] covers keys [t*32,t*32+32) x 32 q-rows
        floatx16 sacc[2];
        __builtin_amdgcn_s_setprio(1);
        #pragma unroll
        for (int t = 0; t < 2; t++) {
            floatx16 sc = {};
            #pragma unroll
            for (int kt = 0; kt < 4; kt++)
                sc = __builtin_amdgcn_mfma_f32_32x32x16_bf16(
                    kf[t * 4 + kt], aq[kt], sc, 0, 0, 0);
            sacc[t] = sc;
        }
        __builtin_amdgcn_s_setprio(0);

        // P = exp2(S'), lane-local partial row sum
        #pragma unroll
        for (int e = 0; e < 16; e++) {
            float pa_ = EXP2(sacc[0][e]);
            float pb_ = EXP2(sacc[1][e]);
            sacc[0][e] = pa_; sacc[1][e] = pb_;
            lsum += pa_ + pb_;
        }

        // PV A-frags in-register: pa[kt] = P[q=l32][kt*16 + h*8 + e]
        short8 pa[4];
        #pragma unroll
        for (int kt = 0; kt < 4; kt++) {
            const int t = kt >> 1, b = (kt & 1) * 8;
            int A1 = cvtpk(sacc[t][b + 0], sacc[t][b + 1]);
            int A2 = cvtpk(sacc[t][b + 2], sacc[t][b + 3]);
            int B1 = cvtpk(sacc[t][b + 4], sacc[t][b + 5]);
            int B2 = cvtpk(sacc[t][b + 6], sacc[t][b + 7]);
            asm volatile("v_permlane32_swap_b32 %0, %1" : "+v"(A1), "+v"(B1));
            asm volatile("v_permlane32_swap_b32 %0, %1" : "+v"(A2), "+v"(B2));
            int4_ w; w[0] = A1; w[1] = A2; w[2] = B1; w[3] = B2;
            __builtin_memcpy(&pa[kt], &w, 16);
        }

        // O += P @ V  (B-frag: V[kt*16 + h*8 + e][d = dt*32 + l32])
        __builtin_amdgcn_s_setprio(1);
        #pragma unroll
        for (int kt = 0; kt < 4; kt++) {
            #pragma unroll
            for (int dt = 0; dt < 2; dt++) {
                const int d = dt * 32 + l32;
                short8 bv = *(const short8*)&vb[d * LDT
                                                + ((kt ^ ((d >> 4) & 3)) * 16 + h * 8)];
                oacc[dt] = __builtin_amdgcn_mfma_f32_32x32x16_bf16(
                    pa[kt], bv, oacc[dt], 0, 0, 0);
            }
        }
        __builtin_amdgcn_s_setprio(0);
    };

    for (int j = 0; j < 15; j++) {
        // issue K fragments for tile j (hidden under barrier + V staging)
        short8 kf[8];
        #pragma unroll
        for (int t = 0; t < 2; t++)
            #pragma unroll
            for (int kt = 0; kt < 4; kt++)
                kf[t * 4 + kt] = *(const short8*)(kb + (size_t)t * krow32 + kt * 16);
        kb += kstep;

        asm volatile("s_waitcnt lgkmcnt(0)" ::: "memory");
        __builtin_amdgcn_s_barrier();   // Vt[j&1] published; Vt[nb] free
        asm volatile("" ::: "memory");

        const int nb = (j + 1) & 1;
        short* vt = &Vt[nb * 64 * LDT];
        #pragma unroll
        for (int e = 0; e < 8; e++) vt[(scol + e) * LDT + (srow ^ vswz)] = va0[e];
        #pragma unroll
        for (int e = 0; e < 8; e++) vt[(scol + 8 + e) * LDT + (srow ^ vswz)] = va1[e];
        va0 = *(const short8*)(vgp);      // V_{j+2} (dummy reload at j=14)
        va1 = *(const short8*)(vgp + 8);
        if (j < 14) vgp += kstep;

        compute(&Vt[(j & 1) * 64 * LDT], kf);
    }
    // last iter (j=15): no staging
    {
        short8 kf[8];
        #pragma unroll
        for (int t = 0; t < 2; t++)
            #pragma unroll
            for (int kt = 0; kt < 4; kt++)
                kf[t * 4 + kt] = *(const short8*)(kb + (size_t)t * krow32 + kt * 16);
        asm volatile("s_waitcnt lgkmcnt(0)" ::: "memory");
        __builtin_amdgcn_s_barrier();
        asm volatile("" ::: "memory");
        compute(&Vt[64 * LDT], kf);
    }

    // epilogue: partial O (unnormalized) -> obuf[half], raw l -> lbuf[half].
    // oacc[dt][reg] = O[q_local = 4h + (reg&3) + 8*(reg>>2)][d = dt*32+l32]
    {
        short* obase = half ? obuf2 : obuf1;
        float* lb = lbuf + (size_t)half * 8192 * 12;
        float lt = lsum + __shfl_xor(lsum, 32, 64);
        #pragma unroll
        for (int m = 0; m < 4; m++) {
            #pragma unroll
            for (int r = 0; r < 4; r++) {
                const int ql = 4 * h + r + 8 * m;
                short* od = obase + (bpos + (size_t)ql * rate) * 768 + head * 64;
                od[l32]      = f2bf(oacc[0][m * 4 + r]);
                od[32 + l32] = f2bf(oacc[1][m * 4 + r]);
            }
        }
        if (lane < 32)
            lb[(bpos + (size_t)l32 * rate) * 12 + head] = lt;
    }
}

// ---- Fused LayerNorm + split-K combine: obuf1+obuf2 -> q section ----------
__global__ __launch_bounds__(256) void ln_inplace(
    short* __restrict__ qkv, const short* __restrict__ obuf1,
    const short* __restrict__ obuf2, const float* __restrict__ lbuf,
    const float* __restrict__ gamma, const float* __restrict__ beta)
{
    const int row  = blockIdx.x * 4 + (threadIdx.x >> 6);
    const int lane = threadIdx.x & 63;
    const short* s1 = obuf1 + (size_t)row * 768;
    const short* s2 = obuf2 + (size_t)row * 768;
    short* dst = qkv + (size_t)row * 2304;

    // heads: first 8 elems (idx lane*8..+7) in head lane>>3;
    // last 4 (idx 512+lane*4..+3) in head 8+(lane>>4)
    const int h1 = lane >> 3;          // 0..7  (groups 0,1)
    const int h2 = 8 + (lane >> 4);    // 8..11 (group 2)
    const bool cov1 = (h1 < 4) || ((row & 1) == 1);
    const bool cov2 = ((row & 3) == 2);
    const float li1 = cov1
        ? 1.0f / (lbuf[row * 12 + h1] + lbuf[8192 * 12 + row * 12 + h1]) : 0.0f;
    const float li2 = cov2
        ? 1.0f / (lbuf[row * 12 + h2] + lbuf[8192 * 12 + row * 12 + h2]) : 0.0f;

    short8  a  = *(const short8*)&s1[lane * 8];
    short4_ b  = *(const short4_*)&s1[512 + lane * 4];
    short8  a2 = *(const short8*)&s2[lane * 8];
    short4_ b2 = *(const short4_*)&s2[512 + lane * 4];
    float v[12];
    #pragma unroll
    for (int e = 0; e < 8; e++)
        v[e] = cov1 ? (bf2f(a[e]) + bf2f(a2[e])) * li1 : 0.0f;
    #pragma unroll
    for (int e = 0; e < 4; e++)
        v[8 + e] = cov2 ? (bf2f(b[e]) + bf2f(b2[e])) * li2 : 0.0f;

    float sum = 0.f, sq = 0.f;
    #pragma unroll
    for (int e = 0; e < 12; e++) { sum += v[e]; sq += v[e] * v[e]; }
    #pragma unroll
    for (int off = 1; off < 64; off <<= 1) {
        sum += __shfl_xor(sum, off, 64);
        sq  += __shfl_xor(sq,  off, 64);
    }
    float mean = sum * (1.0f / 768.0f);
    float var  = sq * (1.0f / 768.0f) - mean * mean;
    float rstd = rsqrtf(var + 1e-5f);

    short8 o8; short4_ o4;
    #pragma unroll
    for (int e = 0; e < 8; e++)
        o8[e] = f2bf((v[e] - mean) * rstd * gamma[lane * 8 + e] + beta[lane * 8 + e]);
    #pragma unroll
    for (int e = 0; e < 4; e++)
        o4[e] = f2bf((v[8 + e] - mean) * rstd * gamma[512 + lane * 4 + e] + beta[512 + lane * 4 + e]);

    *(short8*)&dst[lane * 8] = o8;
    *(short4_*)&dst[512 + lane * 4] = o4;
}

extern "C" void kernel_launch(void* const* d_in, const int* in_sizes, int n_in,
                              void* d_out, int out_size, void* d_ws, size_t ws_size,
                              hipStream_t stream) {
    const float* x     = (const float*)d_in[0];   // [8192,768]
    const float* w_qkv = (const float*)d_in[1];   // [2304,768]
    const float* b_qkv = (const float*)d_in[2];
    const float* w_out = (const float*)d_in[3];   // [768,768]
    const float* b_out = (const float*)d_in[4];
    const float* gamma = (const float*)d_in[5];
    const float* beta  = (const float*)d_in[6];
    float* out = (float*)d_out;                   // [8192,768] fp32

    const int NX = 8192 * 768, NW1 = 2304 * 768, NW2 = 768 * 768;
    char* ws = (char*)d_ws;
    short* qkv   = (short*)(ws);                          // 37.75 MB
    short* xb    = (short*)(ws + (size_t)8192 * 2304 * 2);
    short* wqkvb = xb + NX;
    short* woutb = wqkvb + NW1;
    float* lbuf  = (float*)(woutb + NW2);                 // 2*8192*12 fp32
    short* obuf2 = (short*)(lbuf + 2 * 8192 * 12);        // 12.6 MB
    short* obuf1 = xb;   // xb dead after gemm_qkv; reuse for split-0 partial O

    // 0) one-shot fp32->bf16 conversions (K-rows of w_qkv pre-scaled)
    cvt3<<<dim3((NX + NW1 + NW2) / (256 * 8)), 256, 0, stream>>>(
        x, NX, w_qkv, NW1, w_out, NW2, xb, wqkvb, woutb);

    // 1) qkv = x @ w_qkv^T + b_qkv, covered cells only (16.9 GFLOP)
    gemm_qkv<<<dim3(1344), 256, 0, stream>>>(xb, wqkvb, b_qkv, qkv);

    // 2) split-K in-reg-P attention: partial O -> obuf1/obuf2, l -> lbuf
    dilated_attn<<<dim3(28 * 2 * 16), 256, 0, stream>>>(qkv, obuf1, obuf2, lbuf);

    // 3) LayerNorm + combine -> q section (full 768 cols written)
    ln_inplace<<<dim3(8192 / 4), 256, 0, stream>>>(
        qkv, obuf1, obuf2, lbuf, gamma, beta);

    // 4) out = LN(o) @ w_out^T + b_out (fp32 store)
    gemm_out<<<dim3(768), 256, 0, stream>>>(qkv, woutb, b_out, out);
}

// Round 12
// 202.290 us; speedup vs baseline: 1.0057x; 1.0057x over previous
//
#include <hip/hip_runtime.h>
#include <hip/hip_bf16.h>
#include <cstdint>
#include <cstddef>

// R19: revert R18 (K-direct regressed 46.5->77.8us: per-lane 16B at 4.6KB
//  stride = 32 cache lines/instruction, VMEM serialization) back to R17's
//  proven LDS-K structure, PLUS a content-preserving V-write de-conflict:
//  R18 showed K-path and V-path each contribute ~1.8M conflict cycles.
//  V scatter analysis: thread (srow,scol) writes (scol+e)*72+col; 16*72 ≡ 0
//  (mod 64 shorts) -> all 4 scol-groups hit the SAME 8-bank octave every e
//  (8-way). Fix: group g writes phase ee=(e+g)&15 at step e (static 2-stage
//  vector rotation, no dynamic indexing); residue 8*((e+g)%8)+16*(w^g)+lo
//  puts the 4 groups on distinct octaves (checked for all e,w) -> ~2-way.
//  Same cells, same values, different order; read side untouched.
// cvt3 (K-prescale) / gemm_qkv / gemm_out / ln unchanged from R17.

typedef __attribute__((ext_vector_type(8))) short short8;
typedef __attribute__((ext_vector_type(16))) short short16;
typedef __attribute__((ext_vector_type(4))) short short4_;
typedef __attribute__((ext_vector_type(4))) float float4_;
typedef __attribute__((ext_vector_type(16))) float floatx16;
typedef __attribute__((ext_vector_type(4))) int int4_;

#if __has_builtin(__builtin_amdgcn_exp2f)
#define EXP2(x) __builtin_amdgcn_exp2f(x)
#else
#define EXP2(x) exp2f(x)
#endif

#define QK_SCALE 0.1803368801111244f   // 0.125 * log2(e)

__device__ __forceinline__ float bf2f(short s) {
    unsigned int u = ((unsigned int)(unsigned short)s) << 16;
    float f;
    __builtin_memcpy(&f, &u, 4);
    return f;
}
__device__ __forceinline__ short f2bf(float f) {
    unsigned int u;
    __builtin_memcpy(&u, &f, 4);
    u += 0x7fffu + ((u >> 16) & 1u);   // round-to-nearest-even
    return (short)(u >> 16);
}
__device__ __forceinline__ short8 f8_to_bf8_s(const float* __restrict__ p, float s) {
    float4_ a = *(const float4_*)(p);
    float4_ b = *(const float4_*)(p + 4);
    short8 r;
    r[0] = f2bf(a[0] * s); r[1] = f2bf(a[1] * s);
    r[2] = f2bf(a[2] * s); r[3] = f2bf(a[3] * s);
    r[4] = f2bf(b[0] * s); r[5] = f2bf(b[1] * s);
    r[6] = f2bf(b[2] * s); r[7] = f2bf(b[3] * s);
    return r;
}
__device__ __forceinline__ void gll16(const short* g, short* l) {
    __builtin_amdgcn_global_load_lds(
        (const __attribute__((address_space(1))) unsigned int*)g,
        (__attribute__((address_space(3))) unsigned int*)l, 16, 0, 0);
}
// pack two f32 -> one u32 of 2 bf16 (lo = first arg)
__device__ __forceinline__ int cvtpk(float lo, float hi) {
    int r;
    asm("v_cvt_pk_bf16_f32 %0, %1, %2" : "=v"(r) : "v"(lo), "v"(hi));
    return r;
}

#define LDT 72

// ---- cvt3: fp32->bf16 for x / w_qkv / w_out; scales K-rows of w_qkv ------
__global__ __launch_bounds__(256) void cvt3(
    const float* __restrict__ a, int na, const float* __restrict__ b, int nb,
    const float* __restrict__ c, int nc,
    short* __restrict__ oa, short* __restrict__ ob, short* __restrict__ oc)
{
    int i = (blockIdx.x * 256 + threadIdx.x) * 8;
    if (i < na) {
        *(short8*)&oa[i] = f8_to_bf8_s(a + i, 1.0f);
    } else if (i < na + nb) {
        int j = i - na;
        // w_qkv rows [768,1536) = K section: fold in the softmax scale
        float s = (j >= 768 * 768 && j < 1536 * 768) ? QK_SCALE : 1.0f;
        *(short8*)&ob[j] = f8_to_bf8_s(b + j, s);
    } else {
        int j = i - na - nb;
        if (j < nc) *(short8*)&oc[j] = f8_to_bf8_s(c + j, 1.0f);
    }
}

// ---- gemm_qkv: dilution-aware QKV projection, 128x64 tiles ----------------
// Covered cells only. 1344 blocks: g0 = 768 (64 my x 12 nx, rows stride 1,
// heads 0-3), g1 = 384 (32 x 12, rows 1+2i), g2 = 192 (16 x 12, rows 2+4i).
// gcol = (nx>>2)*768 + g*256 + (nx&3)*64. K-section bias scaled by QK_SCALE
// (W K-rows already scaled in cvt3).
__global__ __launch_bounds__(256) void gemm_qkv(
    const short* __restrict__ A,     // xb [8192,768]
    const short* __restrict__ B,     // wqkvb [2304,768]
    const float* __restrict__ bias,  // b_qkv [2304]
    short* __restrict__ C)           // qkv [8192,2304]
{
    __shared__ short As[128 * 64];   // chunk-swizzled: slot(r,c)=G(r, c^(r&7))
    __shared__ short Bs[64 * 64];

    const int bx = blockIdx.x;
    const int L  = (bx & 7) * 168 + (bx >> 3);   // 1344 = 8 XCDs * 168
    int g, t, rate, off0;
    if (L < 768)       { g = 0; t = L;        rate = 1; off0 = 0; }
    else if (L < 1152) { g = 1; t = L - 768;  rate = 2; off0 = 1; }
    else               { g = 2; t = L - 1152; rate = 4; off0 = 2; }
    const int nx = t % 12, my = t / 12;         // nx fastest: A-panel shared
    const int ncol0 = (nx >> 2) * 768 + g * 256 + (nx & 3) * 64;
    const int m0 = my * 128;                    // local (gathered) row base
    const float bscale = ((nx >> 2) == 1) ? QK_SCALE : 1.0f;

    const int tid  = threadIdx.x;
    const int wave = tid >> 6, lane = tid & 63;
    const int quad = lane >> 4, l16 = lane & 15;
    const int lrow   = lane >> 3;
    const int lchunk = (lane & 7) ^ lrow;

    const short* Abase = A + (size_t)(off0 + (m0 + wave * 32 + lrow) * rate) * 768
                           + lchunk * 8;
    const short* Bbase = B + (size_t)(ncol0 + wave * 16 + lrow) * 768 + lchunk * 8;
    short* AsW = &As[(wave * 32) * 64];
    short* BsW = &Bs[(wave * 16) * 64];
    const size_t arowstep = (size_t)8 * rate * 768;

    float4_ acc[2][4] = {};

    for (int k0 = 0; k0 < 768; k0 += 64) {
        __syncthreads();
        #pragma unroll
        for (int i = 0; i < 4; i++)
            gll16(Abase + (size_t)i * arowstep + k0, AsW + (i * 8) * 64);
        #pragma unroll
        for (int i = 0; i < 2; i++)
            gll16(Bbase + (size_t)(i * 8) * 768 + k0, BsW + (i * 8) * 64);
        __syncthreads();
        #pragma unroll
        for (int ks = 0; ks < 2; ks++) {
            const int ca = ((ks * 4 + quad) ^ (l16 & 7)) * 8;
            short8 af[2], bf[4];
            #pragma unroll
            for (int mt = 0; mt < 2; mt++)
                af[mt] = *(const short8*)&As[(wave * 32 + mt * 16 + l16) * 64 + ca];
            #pragma unroll
            for (int nt = 0; nt < 4; nt++)
                bf[nt] = *(const short8*)&Bs[(nt * 16 + l16) * 64 + ca];
            #pragma unroll
            for (int mt = 0; mt < 2; mt++)
                #pragma unroll
                for (int nt = 0; nt < 4; nt++)
                    acc[mt][nt] = __builtin_amdgcn_mfma_f32_16x16x32_bf16(
                        af[mt], bf[nt], acc[mt][nt], 0, 0, 0);
        }
    }

    #pragma unroll
    for (int nt = 0; nt < 4; nt++) {
        const int gcol = ncol0 + nt * 16 + l16;
        const float bv = bias[gcol] * bscale;
        #pragma unroll
        for (int mt = 0; mt < 2; mt++) {
            #pragma unroll
            for (int r = 0; r < 4; r++) {
                const int rl = m0 + wave * 32 + mt * 16 + quad * 4 + r;
                const size_t grow = (size_t)off0 + (size_t)rl * rate;
                C[grow * 2304 + gcol] = f2bf(acc[mt][nt][r] + bv);
            }
        }
    }
}

// ---- gemm_out: out-projection, 128x64 tiles, fp32 store -------------------
// out[row, col] = LN(o)[row,:768] @ w_out[col,:]^T + b_out[col].
// 768 blocks = 12 nx x 64 my, XCD swizzle 8x96.
__global__ __launch_bounds__(256) void gemm_out(
    const short* __restrict__ A,     // qkv [8192,2304], q section = LN(o)
    const short* __restrict__ B,     // woutb [768,768]
    const float* __restrict__ bias,  // b_out [768]
    float* __restrict__ C)           // out [8192,768] fp32
{
    __shared__ short As[128 * 64];
    __shared__ short Bs[64 * 64];

    const int bx = blockIdx.x;
    const int L  = (bx & 7) * 96 + (bx >> 3);   // 768 = 8 XCDs * 96
    const int nx = L % 12, my = L / 12;
    const int n0 = nx * 64, m0 = my * 128;

    const int tid  = threadIdx.x;
    const int wave = tid >> 6, lane = tid & 63;
    const int quad = lane >> 4, l16 = lane & 15;
    const int lrow   = lane >> 3;
    const int lchunk = (lane & 7) ^ lrow;

    const short* Abase = A + (size_t)(m0 + wave * 32 + lrow) * 2304 + lchunk * 8;
    const short* Bbase = B + (size_t)(n0 + wave * 16 + lrow) * 768 + lchunk * 8;
    short* AsW = &As[(wave * 32) * 64];
    short* BsW = &Bs[(wave * 16) * 64];

    float4_ acc[2][4] = {};

    for (int k0 = 0; k0 < 768; k0 += 64) {
        __syncthreads();
        #pragma unroll
        for (int i = 0; i < 4; i++)
            gll16(Abase + (size_t)(i * 8) * 2304 + k0, AsW + (i * 8) * 64);
        #pragma unroll
        for (int i = 0; i < 2; i++)
            gll16(Bbase + (size_t)(i * 8) * 768 + k0, BsW + (i * 8) * 64);
        __syncthreads();
        #pragma unroll
        for (int ks = 0; ks < 2; ks++) {
            const int ca = ((ks * 4 + quad) ^ (l16 & 7)) * 8;
            short8 af[2], bf[4];
            #pragma unroll
            for (int mt = 0; mt < 2; mt++)
                af[mt] = *(const short8*)&As[(wave * 32 + mt * 16 + l16) * 64 + ca];
            #pragma unroll
            for (int nt = 0; nt < 4; nt++)
                bf[nt] = *(const short8*)&Bs[(nt * 16 + l16) * 64 + ca];
            #pragma unroll
            for (int mt = 0; mt < 2; mt++)
                #pragma unroll
                for (int nt = 0; nt < 4; nt++)
                    acc[mt][nt] = __builtin_amdgcn_mfma_f32_16x16x32_bf16(
                        af[mt], bf[nt], acc[mt][nt], 0, 0, 0);
        }
    }

    #pragma unroll
    for (int nt = 0; nt < 4; nt++) {
        const int col = n0 + nt * 16 + l16;
        const float bv = bias[col];
        #pragma unroll
        for (int mt = 0; mt < 2; mt++) {
            #pragma unroll
            for (int r = 0; r < 4; r++) {
                const int row = m0 + wave * 32 + mt * 16 + quad * 4 + r;
                C[(size_t)row * 768 + col] = acc[mt][nt][r] + bv;
            }
        }
    }
}

// ---- Split-K in-register-P dilated attention, counted-vmcnt pipeline ------
// Grid: 896 = 28 sh * 2 half * 16 qt (XCD-chunk swizzled, qt fastest).
// Block 256 = 4 waves; wave w owns q-rows [w*32, w*32+32). 16 K/V tiles of
// 64 keys, double-buffered. Raw s_barrier + counted vmcnt: K-DMA and V
// register-prefetch span phases (never drained to 0 mid-loop).
// K pre-scaled by QK_SCALE at projection; Q loaded raw.
// V-write de-conflict: scol-group g writes phase ee=(e+g)&15 at step e
// (static vector rotation) -> 4 groups on distinct bank octaves.
__global__ __launch_bounds__(256, 4) void dilated_attn(
    const short* __restrict__ qkv, short* __restrict__ obuf1,
    short* __restrict__ obuf2, float* __restrict__ lbuf)
{
    __shared__ short Ks[2 * 64 * 64];   // K[key][d], chunk-XOR swizzled (DMA)
    __shared__ short Vt[2 * 64 * LDT];  // Vt[d][key], key cols XOR-swizzled

    const int bx = blockIdx.x;
    const int L  = (bx & 7) * 112 + (bx >> 3);   // 896 = 8 XCDs * 112
    const int qt   = L & 15;
    const int half = (L >> 4) & 1;
    const int sh   = L >> 5;   // 0..27

    int g, seg, s, rate, off0;
    if (sh < 16)      { g = 0; seg = sh >> 2;        s = 2048; rate = 1; off0 = 0; }
    else if (sh < 24) { g = 1; seg = (sh - 16) >> 2; s = 4096; rate = 2; off0 = 1; }
    else              { g = 2; seg = 0;              s = 8192; rate = 4; off0 = 2; }
    const int head = g * 4 + (sh & 3);

    const int tid  = threadIdx.x;
    const int wave = tid >> 6, lane = tid & 63;
    const int h = lane >> 5, l32 = lane & 31;
    const int srow = tid >> 2, scol = (tid & 3) * 16;   // V-staging map
    const int sg   = tid & 3;                            // scol group
    const int vswz = scol;

    // ---- Q frags (B-operand of swapped QK): lane (h,l32) holds
    // Q[q = qt*128+wave*32+l32][kt*16 + h*8 + e], raw (K carries the scale).
    const size_t bpos = (size_t)seg * s + off0
                      + (size_t)(qt * 128 + wave * 32) * rate;
    short8 aq[4];
    {
        const short* qsrc = qkv + (bpos + (size_t)l32 * rate) * 2304
                                + head * 64 + h * 8;
        #pragma unroll
        for (int kt = 0; kt < 4; kt++)
            aq[kt] = *(const short8*)(qsrc + kt * 16);
    }

    // staging maps (key index offset by half*1024 dilated positions)
    const int krow0  = wave * 8 + (lane >> 3);
    const int kchunk = (lane & 7) ^ (lane >> 3);
    const size_t kstep = (size_t)64 * rate * 2304;
    const size_t kq0 = (size_t)seg * s + off0 + (size_t)(half * 1024) * rate;
    const short* kg0 = qkv + (kq0 + (size_t)krow0 * rate) * 2304
                           + 768 + head * 64 + kchunk * 8;
    const short* kg1 = kg0 + (size_t)32 * rate * 2304;
    const short* vgp = qkv + (kq0 + (size_t)srow * rate) * 2304
                           + 1536 + head * 64 + scol;
    const int kofsA = (wave * 8) * 64;
    const int kofsB = kofsA + 32 * 64;

    // staggered V scatter: group sg writes phase ee=(e+sg)&15 at step e.
    auto stageV = [&](short* vt, short8 a0, short8 a1) {
        short16 v;
        #pragma unroll
        for (int e = 0; e < 8; e++) { v[e] = a0[e]; v[8 + e] = a1[e]; }
        short16 r1 = __builtin_shufflevector(v, v,
            1, 2, 3, 4, 5, 6, 7, 8, 9, 10, 11, 12, 13, 14, 15, 0);
        v = (sg & 1) ? r1 : v;
        short16 r2 = __builtin_shufflevector(v, v,
            2, 3, 4, 5, 6, 7, 8, 9, 10, 11, 12, 13, 14, 15, 0, 1);
        v = (sg & 2) ? r2 : v;
        // now v[e] = orig[(e+sg)&15]
        #pragma unroll
        for (int e = 0; e < 16; e++) {
            const int ee = (e + sg) & 15;
            vt[(scol + ee) * LDT + (srow ^ vswz)] = v[e];
        }
    };

    // ---- prologue: K0 DMA into buf0; V0 regs -> buf0; va := V1 ------------
    gll16(kg0, &Ks[kofsA]);
    gll16(kg1, &Ks[kofsB]);
    kg0 += kstep; kg1 += kstep;
    short8 va0 = *(const short8*)(vgp);
    short8 va1 = *(const short8*)(vgp + 8);
    vgp += kstep;
    // compiler inserts counted vmcnt before consuming va0/va1 (drains K0 too)
    stageV(&Vt[0], va0, va1);
    va0 = *(const short8*)(vgp);      // V tile 1
    va1 = *(const short8*)(vgp + 8);
    vgp += kstep;
    // outstanding entering loop: va_V1(2)

    float lsum = 0.f;
    floatx16 oacc[2] = {};

    auto compute = [&](const short* kb, const short* vb) {
        // S'^T = K' Q^T : sacc[t] covers keys [t*32,t*32+32) x 32 q-rows
        floatx16 sacc[2] = {};
        __builtin_amdgcn_s_setprio(1);
        #pragma unroll
        for (int kt = 0; kt < 4; kt++) {
            #pragma unroll
            for (int t = 0; t < 2; t++) {
                short8 ak = *(const short8*)&kb[(t * 32 + l32) * 64
                                                + (((kt * 2 + h) ^ (l32 & 7)) * 8)];
                sacc[t] = __builtin_amdgcn_mfma_f32_32x32x16_bf16(
                    ak, aq[kt], sacc[t], 0, 0, 0);
            }
        }
        __builtin_amdgcn_s_setprio(0);

        // P = exp2(S'), lane-local partial row sum
        #pragma unroll
        for (int e = 0; e < 16; e++) {
            float pa_ = EXP2(sacc[0][e]);
            float pb_ = EXP2(sacc[1][e]);
            sacc[0][e] = pa_; sacc[1][e] = pb_;
            lsum += pa_ + pb_;
        }

        // PV A-frags in-register: pa[kt] = P[q=l32][kt*16 + h*8 + e]
        short8 pa[4];
        #pragma unroll
        for (int kt = 0; kt < 4; kt++) {
            const int t = kt >> 1, b = (kt & 1) * 8;
            int A1 = cvtpk(sacc[t][b + 0], sacc[t][b + 1]);
            int A2 = cvtpk(sacc[t][b + 2], sacc[t][b + 3]);
            int B1 = cvtpk(sacc[t][b + 4], sacc[t][b + 5]);
            int B2 = cvtpk(sacc[t][b + 6], sacc[t][b + 7]);
            asm volatile("v_permlane32_swap_b32 %0, %1" : "+v"(A1), "+v"(B1));
            asm volatile("v_permlane32_swap_b32 %0, %1" : "+v"(A2), "+v"(B2));
            int4_ w; w[0] = A1; w[1] = A2; w[2] = B1; w[3] = B2;
            __builtin_memcpy(&pa[kt], &w, 16);
        }

        // O += P @ V  (B-frag: V[kt*16 + h*8 + e][d = dt*32 + l32])
        __builtin_amdgcn_s_setprio(1);
        #pragma unroll
        for (int kt = 0; kt < 4; kt++) {
            #pragma unroll
            for (int dt = 0; dt < 2; dt++) {
                const int d = dt * 32 + l32;
                short8 bv = *(const short8*)&vb[d * LDT
                                                + ((kt ^ ((d >> 4) & 3)) * 16 + h * 8)];
                oacc[dt] = __builtin_amdgcn_mfma_f32_32x32x16_bf16(
                    pa[kt], bv, oacc[dt], 0, 0, 0);
            }
        }
        __builtin_amdgcn_s_setprio(0);
    };

    for (int j = 0; j < 15; j++) {
        // K_j DMA landed (2 newest — va_{j+1} — may fly); own ds ops retired
        asm volatile("s_waitcnt vmcnt(2)" ::: "memory");
        asm volatile("s_waitcnt lgkmcnt(0)" ::: "memory");
        __builtin_amdgcn_s_barrier();   // buf[j&1] fully valid for all waves

        const int nb = (j + 1) & 1;
        gll16(kg0, &Ks[nb * 4096 + kofsA]);   // K_{j+1}: flies across phases
        gll16(kg1, &Ks[nb * 4096 + kofsB]);
        kg0 += kstep; kg1 += kstep;
        // wait va_{j+1} only (K_{j+1} stays outstanding)
        asm volatile("s_waitcnt vmcnt(2)" ::: "memory");
        stageV(&Vt[nb * 64 * LDT], va0, va1);
        if (j < 14) {
            va0 = *(const short8*)(vgp);      // va_{j+2}: flies across phases
            va1 = *(const short8*)(vgp + 8);
            vgp += kstep;
        }
        compute(&Ks[(j & 1) * 4096], &Vt[(j & 1) * 64 * LDT]);
    }
    // last iter (j=15): only K_15(2) outstanding
    asm volatile("s_waitcnt vmcnt(0)" ::: "memory");
    asm volatile("s_waitcnt lgkmcnt(0)" ::: "memory");
    __builtin_amdgcn_s_barrier();
    compute(&Ks[4096], &Vt[64 * LDT]);

    // epilogue: partial O (unnormalized) -> obuf[half], raw l -> lbuf[half].
    // oacc[dt][reg] = O[q_local = 4h + (reg&3) + 8*(reg>>2)][d = dt*32+l32]
    {
        short* obase = half ? obuf2 : obuf1;
        float* lb = lbuf + (size_t)half * 8192 * 12;
        float lt = lsum + __shfl_xor(lsum, 32, 64);
        #pragma unroll
        for (int m = 0; m < 4; m++) {
            #pragma unroll
            for (int r = 0; r < 4; r++) {
                const int ql = 4 * h + r + 8 * m;
                short* od = obase + (bpos + (size_t)ql * rate) * 768 + head * 64;
                od[l32]      = f2bf(oacc[0][m * 4 + r]);
                od[32 + l32] = f2bf(oacc[1][m * 4 + r]);
            }
        }
        if (lane < 32)
            lb[(bpos + (size_t)l32 * rate) * 12 + head] = lt;
    }
}

// ---- Fused LayerNorm + split-K combine: obuf1+obuf2 -> q section ----------
__global__ __launch_bounds__(256) void ln_inplace(
    short* __restrict__ qkv, const short* __restrict__ obuf1,
    const short* __restrict__ obuf2, const float* __restrict__ lbuf,
    const float* __restrict__ gamma, const float* __restrict__ beta)
{
    const int row  = blockIdx.x * 4 + (threadIdx.x >> 6);
    const int lane = threadIdx.x & 63;
    const short* s1 = obuf1 + (size_t)row * 768;
    const short* s2 = obuf2 + (size_t)row * 768;
    short* dst = qkv + (size_t)row * 2304;

    // heads: first 8 elems (idx lane*8..+7) in head lane>>3;
    // last 4 (idx 512+lane*4..+3) in head 8+(lane>>4)
    const int h1 = lane >> 3;          // 0..7  (groups 0,1)
    const int h2 = 8 + (lane >> 4);    // 8..11 (group 2)
    const bool cov1 = (h1 < 4) || ((row & 1) == 1);
    const bool cov2 = ((row & 3) == 2);
    const float li1 = cov1
        ? 1.0f / (lbuf[row * 12 + h1] + lbuf[8192 * 12 + row * 12 + h1]) : 0.0f;
    const float li2 = cov2
        ? 1.0f / (lbuf[row * 12 + h2] + lbuf[8192 * 12 + row * 12 + h2]) : 0.0f;

    short8  a  = *(const short8*)&s1[lane * 8];
    short4_ b  = *(const short4_*)&s1[512 + lane * 4];
    short8  a2 = *(const short8*)&s2[lane * 8];
    short4_ b2 = *(const short4_*)&s2[512 + lane * 4];
    float v[12];
    #pragma unroll
    for (int e = 0; e < 8; e++)
        v[e] = cov1 ? (bf2f(a[e]) + bf2f(a2[e])) * li1 : 0.0f;
    #pragma unroll
    for (int e = 0; e < 4; e++)
        v[8 + e] = cov2 ? (bf2f(b[e]) + bf2f(b2[e])) * li2 : 0.0f;

    float sum = 0.f, sq = 0.f;
    #pragma unroll
    for (int e = 0; e < 12; e++) { sum += v[e]; sq += v[e] * v[e]; }
    #pragma unroll
    for (int off = 1; off < 64; off <<= 1) {
        sum += __shfl_xor(sum, off, 64);
        sq  += __shfl_xor(sq,  off, 64);
    }
    float mean = sum * (1.0f / 768.0f);
    float var  = sq * (1.0f / 768.0f) - mean * mean;
    float rstd = rsqrtf(var + 1e-5f);

    short8 o8; short4_ o4;
    #pragma unroll
    for (int e = 0; e < 8; e++)
        o8[e] = f2bf((v[e] - mean) * rstd * gamma[lane * 8 + e] + beta[lane * 8 + e]);
    #pragma unroll
    for (int e = 0; e < 4; e++)
        o4[e] = f2bf((v[8 + e] - mean) * rstd * gamma[512 + lane * 4 + e] + beta[512 + lane * 4 + e]);

    *(short8*)&dst[lane * 8] = o8;
    *(short4_*)&dst[512 + lane * 4] = o4;
}

extern "C" void kernel_launch(void* const* d_in, const int* in_sizes, int n_in,
                              void* d_out, int out_size, void* d_ws, size_t ws_size,
                              hipStream_t stream) {
    const float* x     = (const float*)d_in[0];   // [8192,768]
    const float* w_qkv = (const float*)d_in[1];   // [2304,768]
    const float* b_qkv = (const float*)d_in[2];
    const float* w_out = (const float*)d_in[3];   // [768,768]
    const float* b_out = (const float*)d_in[4];
    const float* gamma = (const float*)d_in[5];
    const float* beta  = (const float*)d_in[6];
    float* out = (float*)d_out;                   // [8192,768] fp32

    const int NX = 8192 * 768, NW1 = 2304 * 768, NW2 = 768 * 768;
    char* ws = (char*)d_ws;
    short* qkv   = (short*)(ws);                          // 37.75 MB
    short* xb    = (short*)(ws + (size_t)8192 * 2304 * 2);
    short* wqkvb = xb + NX;
    short* woutb = wqkvb + NW1;
    float* lbuf  = (float*)(woutb + NW2);                 // 2*8192*12 fp32
    short* obuf2 = (short*)(lbuf + 2 * 8192 * 12);        // 12.6 MB
    short* obuf1 = xb;   // xb dead after gemm_qkv; reuse for split-0 partial O

    // 0) one-shot fp32->bf16 conversions (K-rows of w_qkv pre-scaled)
    cvt3<<<dim3((NX + NW1 + NW2) / (256 * 8)), 256, 0, stream>>>(
        x, NX, w_qkv, NW1, w_out, NW2, xb, wqkvb, woutb);

    // 1) qkv = x @ w_qkv^T + b_qkv, covered cells only (16.9 GFLOP)
    gemm_qkv<<<dim3(1344), 256, 0, stream>>>(xb, wqkvb, b_qkv, qkv);

    // 2) split-K in-reg-P attention: partial O -> obuf1/obuf2, l -> lbuf
    dilated_attn<<<dim3(28 * 2 * 16), 256, 0, stream>>>(qkv, obuf1, obuf2, lbuf);

    // 3) LayerNorm + combine -> q section (full 768 cols written)
    ln_inplace<<<dim3(8192 / 4), 256, 0, stream>>>(
        qkv, obuf1, obuf2, lbuf, gamma, beta);

    // 4) out = LN(o) @ w_out^T + b_out (fp32 store)
    gemm_out<<<dim3(768), 256, 0, stream>>>(qkv, woutb, b_out, out);
}